// Round 13
// baseline (147.931 us; speedup 1.0000x reference)
//
#include <hip/hip_runtime.h>
#include <math.h>

// InfoNCE (NT-Xent), N=8192, D=128, fp32 in, scalar fp32 out.
// Unified stacked Gram G=[g1n;g2n]*sqrt(5*log2e), fp8 e4m3, 2N x 128.
// P layout (r19, OPERAND-MAJOR): row group g=r>>5 at g*4096; operand block
// (kc,lhi) at +(kc*2+lhi)*1024; lane row l32=r&31 at +l32*32; frag i=0..3
// (f = kc*8+lhi*4+i) at +i*8. One MFMA operand = 32 CONTIGUOUS bytes/lane.
// Lower-triangle strip pairs. MFMA = MX-scaled 32x32x64 f8f6f4, unit scales.
//
// r19: HALVE VMEM INSTRS + FIX THE LOSS KERNEL. r18 ledger: gram issue work
// ~18us vs 64.6us wall (35% busy, stall-bound at 2.25 waves/SIMD); and
// ~67us of total lives OUTSIDE gram every round -- loss_reduce ran 8192
// threads (=128 waves on 256 CUs, 1/4 wave per CU) x 290 serial scalar
// loads. Changes: (1) operand-contiguous P: load_op = 2x16B (was 4x8B),
// gram VMEM instrs 16->8 per tile, normalize stores 2x16B; (2) loss_reduce
// = 256 blocks x (32 rows x 8 slot-groups), coalesced, LDS combine;
// (3) launch_bounds(256,4) (cap 128 >= ~116 live; spill tripwire =
// WRITE_SIZE must stay 9.28MB logical).
// Partials part[145][2N]: slots 0..16 row (y; z disjoint), 17+(4y+t)*2+z
// col (y<16); diag tile writes zeros -> uniform reduce.

constexpr int D = 128;
constexpr float E5 = 148.4131591025766f;   // e^5 (diag self-term)
constexpr int NSLOT = 145;

typedef __attribute__((ext_vector_type(16))) float f32x16;  // 32x32 MFMA acc
typedef __attribute__((ext_vector_type(8)))  int   v8i;     // 32-byte operand
typedef __attribute__((ext_vector_type(4)))  long  v4l;
typedef __attribute__((ext_vector_type(2)))  long  v2l;

// 32 rows per block, 8 threads per row (16 floats each). Per-row reduce via
// 3-step shuffle in the 8-lane group. P stores: one 16B store per matrix
// (frags 2t,2t+1 are contiguous in the operand-major layout).
__global__ __launch_bounds__(256) void normalize_kernel(
    const float4* __restrict__ h1, const float4* __restrict__ h2,
    unsigned char* __restrict__ P, float* __restrict__ d12,
    float* __restrict__ out, int N)
{
    const float SC = sqrtf(5.0f * 1.44269504088896340736f);  // sqrt(5*log2e)
    if (blockIdx.x == 0 && threadIdx.x == 0) out[0] = 0.f;

    const int tx   = threadIdx.x;
    const int rloc = tx >> 3;                 // 0..31  (row within block)
    const int t    = tx & 7;                  // 0..7   (16-float chunk)
    const int row  = blockIdx.x * 32 + rloc;

    float4 u[4], w[4];
#pragma unroll
    for (int i = 0; i < 4; ++i) {
        u[i] = h1[(size_t)row * 32 + t * 4 + i];
        w[i] = h2[(size_t)row * 32 + t * 4 + i];
    }
    float ss1 = 0.f, ss2 = 0.f, s12 = 0.f;
#pragma unroll
    for (int i = 0; i < 4; ++i) {
        ss1 += u[i].x*u[i].x + u[i].y*u[i].y + u[i].z*u[i].z + u[i].w*u[i].w;
        ss2 += w[i].x*w[i].x + w[i].y*w[i].y + w[i].z*w[i].z + w[i].w*w[i].w;
        s12 += u[i].x*w[i].x + u[i].y*w[i].y + u[i].z*w[i].z + u[i].w*w[i].w;
    }
#pragma unroll
    for (int off = 4; off > 0; off >>= 1) {   // reduce over the 8-lane group
        ss1 += __shfl_xor(ss1, off, 64);
        ss2 += __shfl_xor(ss2, off, 64);
        s12 += __shfl_xor(s12, off, 64);
    }
    float n1 = fmaxf(sqrtf(ss1), 1e-12f);
    float n2 = fmaxf(sqrtf(ss2), 1e-12f);
    float c1 = SC / n1, c2 = SC / n2;
    if (t == 0) d12[row] = 5.f * s12 / (n1 * n2);

    // pack 16 fp8 bytes per matrix: frags 2t (k=16t..+7) and 2t+1 (+8..+15)
    int u0 = __builtin_amdgcn_cvt_pk_fp8_f32(u[0].x*c1, u[0].y*c1, 0, false);
    u0     = __builtin_amdgcn_cvt_pk_fp8_f32(u[0].z*c1, u[0].w*c1, u0, true);
    int u1 = __builtin_amdgcn_cvt_pk_fp8_f32(u[1].x*c1, u[1].y*c1, 0, false);
    u1     = __builtin_amdgcn_cvt_pk_fp8_f32(u[1].z*c1, u[1].w*c1, u1, true);
    int u2 = __builtin_amdgcn_cvt_pk_fp8_f32(u[2].x*c1, u[2].y*c1, 0, false);
    u2     = __builtin_amdgcn_cvt_pk_fp8_f32(u[2].z*c1, u[2].w*c1, u2, true);
    int u3 = __builtin_amdgcn_cvt_pk_fp8_f32(u[3].x*c1, u[3].y*c1, 0, false);
    u3     = __builtin_amdgcn_cvt_pk_fp8_f32(u[3].z*c1, u[3].w*c1, u3, true);
    int w0 = __builtin_amdgcn_cvt_pk_fp8_f32(w[0].x*c2, w[0].y*c2, 0, false);
    w0     = __builtin_amdgcn_cvt_pk_fp8_f32(w[0].z*c2, w[0].w*c2, w0, true);
    int w1 = __builtin_amdgcn_cvt_pk_fp8_f32(w[1].x*c2, w[1].y*c2, 0, false);
    w1     = __builtin_amdgcn_cvt_pk_fp8_f32(w[1].z*c2, w[1].w*c2, w1, true);
    int w2 = __builtin_amdgcn_cvt_pk_fp8_f32(w[2].x*c2, w[2].y*c2, 0, false);
    w2     = __builtin_amdgcn_cvt_pk_fp8_f32(w[2].z*c2, w[2].w*c2, w2, true);
    int w3 = __builtin_amdgcn_cvt_pk_fp8_f32(w[3].x*c2, w[3].y*c2, 0, false);
    w3     = __builtin_amdgcn_cvt_pk_fp8_f32(w[3].z*c2, w[3].w*c2, w3, true);

    unsigned long long ulo = (unsigned)u0 | ((unsigned long long)(unsigned)u1 << 32);
    unsigned long long uhi = (unsigned)u2 | ((unsigned long long)(unsigned)u3 << 32);
    unsigned long long wlo = (unsigned)w0 | ((unsigned long long)(unsigned)w1 << 32);
    unsigned long long whi = (unsigned)w2 | ((unsigned long long)(unsigned)w3 << 32);

    // operand-major dest: frag f=2t -> operand (c=t>>2, h=(t>>1)&1),
    // slot idx=(2t)&3; frags 2t,2t+1 contiguous -> one 16B store/matrix.
    const size_t opoff = (size_t)((t >> 2) * 2 + ((t >> 1) & 1)) * 1024
                       + (size_t)rloc * 32 + (size_t)((2 * t) & 3) * 8;
    size_t b1 = (size_t)blockIdx.x * 4096 + opoff;
    size_t b2 = ((size_t)(N >> 5) + blockIdx.x) * 4096 + opoff;
    *(v2l*)(P + b1) = (v2l){(long)ulo, (long)uhi};
    *(v2l*)(P + b2) = (v2l){(long)wlo, (long)whi};
}

// Load a 32-byte K=64 operand: CONTIGUOUS 32B at p (2 x dwordx4).
__device__ __forceinline__ v8i load_op(const unsigned char* p) {
    v2l q0 = *(const v2l*)(p);
    v2l q1 = *(const v2l*)(p + 16);
    v4l t = {q0[0], q0[1], q1[0], q1[1]};
    return __builtin_bit_cast(v8i, t);
}

// Strips of 128 rows over 2N=16384 -> 128 strips. Block (I, y, z):
// rows = I*128 + z*64 .. +63; y<16: tiles J=(I+4y+t)&127, t=0..3, rows+cols;
// y==16: J=(I+64)&127, rows ONLY (pair computed from both sides).
// Block = 256 thr, 4 waves: wr=row 32-half, wc=col 64-half; wave tile 32x64.
// Row group g (32 rows): P + g*4096; operand (kc,lhi) at +(kc*2+lhi)*1024;
// lane row at +l32*32.
__global__ __launch_bounds__(256, 4) void gram_mfma_kernel(
    const unsigned char* __restrict__ P, float* __restrict__ part, int N)
{
    const int I = blockIdx.x;
    const int z = blockIdx.z;
    int nT = 4, dBase = 0;
    bool doCols = true;
    if (blockIdx.y < 16) { dBase = blockIdx.y * 4; }
    else                 { nT = 1; dBase = 64; doCols = false; }

    __shared__ float ldsRow[64];
    __shared__ float ldsCol[4][128];

    const int tx   = threadIdx.x;
    const int lane = tx & 63;
    const int l32  = lane & 31, lhi = lane >> 5;
    const int wid  = tx >> 6;
    const int wr   = wid >> 1;          // 0..1: 32-row half of the 64 rows
    const int wc   = wid & 1;           // 0..1: 64-col half
    const int iBase = I * 128 + z * 64;
    const int fOff = lhi * 1024 + l32 * 32;   // operand sub-block + lane row

    // zero block-local accumulators (64 + 512 floats, 256 thr)
    if (tx < 64) ldsRow[tx] = 0.f;
    ((float*)ldsCol)[tx] = 0.f;
    ((float*)ldsCol)[tx + 256] = 0.f;
    __syncthreads();

    // A-operand: rows iBase + wr*32 + l32 -> row group I*4 + z*2 + wr
    v8i a[2];
    {
        const unsigned char* xp =
            P + (size_t)(I * 4 + z * 2 + wr) * 4096 + fOff;
        a[0] = load_op(xp);
        a[1] = load_op(xp + 2048);
    }

    float racc[16];
#pragma unroll
    for (int r = 0; r < 16; ++r) racc[r] = 0.f;

    const int j0 = wc * 64 + l32;

    // Prologue: tile 0's B operands into registers.
    v8i b0[2], b1[2];
    {
        const int J0 = (I + dBase) & 127;
        const unsigned char* pb =
            P + (size_t)(J0 * 4 + wc * 2) * 4096 + fOff;
#pragma unroll
        for (int kc = 0; kc < 2; ++kc) {
            b0[kc] = load_op(pb + kc * 2048);
            b1[kc] = load_op(pb + 4096 + kc * 2048);
        }
    }

#pragma unroll
    for (int t = 0; t < 4; ++t) {
        if (t >= nT) break;

        // Unconditional 1-deep prefetch (clamped on last iter).
        const int tn = (t + 1 < nT) ? t + 1 : t;
        const int Jn = (I + dBase + tn) & 127;
        const unsigned char* pn =
            P + (size_t)(Jn * 4 + wc * 2) * 4096 + fOff;
        v8i n0[2], n1[2];
#pragma unroll
        for (int kc = 0; kc < 2; ++kc) {
            n0[kc] = load_op(pn + kc * 2048);
            n1[kc] = load_op(pn + 4096 + kc * 2048);
        }

        f32x16 acc0, acc1;
#pragma unroll
        for (int r = 0; r < 16; ++r) { acc0[r] = 0.f; acc1[r] = 0.f; }

#pragma unroll
        for (int kc = 0; kc < 2; ++kc) {
            acc0 = __builtin_amdgcn_mfma_scale_f32_32x32x64_f8f6f4(
                a[kc], b0[kc], acc0, 0, 0, 0, 127, 0, 127);
            acc1 = __builtin_amdgcn_mfma_scale_f32_32x32x64_f8f6f4(
                a[kc], b1[kc], acc1, 0, 0, 0, 127, 0, 127);
        }

        // epilogue: exp2; row sums into racc (regs), col sums into LDS
        float c0 = 0.f, c1 = 0.f;
#pragma unroll
        for (int r = 0; r < 16; ++r) {
            float e0 = __builtin_amdgcn_exp2f(acc0[r]);
            float e1 = __builtin_amdgcn_exp2f(acc1[r]);
            racc[r] += e0 + e1;
            c0 += e0;
            c1 += e1;
        }
        if (doCols && (dBase + t) != 0) {  // diag tile: col sums == row sums
            c0 += __shfl_xor(c0, 32, 64);  // merge lhi halves
            c1 += __shfl_xor(c1, 32, 64);
            if (lane < 32) {               // on-CU ds atomics
                atomicAdd(&ldsCol[t][j0], c0);
                atomicAdd(&ldsCol[t][j0 + 32], c1);
            }
        }

        // rotate prefetched operands in
        b0[0] = n0[0]; b0[1] = n0[1];
        b1[0] = n1[0]; b1[1] = n1[1];
    }

    // flush row sums: butterfly over 32 col-lanes; C row=(r&3)+8*(r>>2)+4*lhi
#pragma unroll
    for (int r = 0; r < 16; ++r) {
        float s = racc[r];
#pragma unroll
        for (int off = 1; off < 32; off <<= 1)
            s += __shfl_xor(s, off, 64);
        if (l32 == 0) {
            int rowm = (r & 3) + 8 * (r >> 2) + 4 * lhi;
            atomicAdd(&ldsRow[wr * 32 + rowm], s);
        }
    }

    __syncthreads();

    // writeout: plain coalesced stores of per-block partials.
    {
        const int y = blockIdx.y;
        if (tx < 64)
            part[(size_t)y * (2 * N) + iBase + tx] = ldsRow[tx];
        if (doCols && tx < 128) {
#pragma unroll
            for (int t = 0; t < 4; ++t) {
                const int J = (I + dBase + t) & 127;
                const size_t slot = (size_t)(17 + (y * 4 + t) * 2 + z);
                part[slot * (2 * N) + (size_t)J * 128 + tx] = ldsCol[t][tx];
            }
        }
    }
}

// Block = 32 rows x 8 slot-groups (256 thr, 256 blocks). Thread (s,j) sums
// slots s, s+8, ... for row i=blk*32+j (both halves); LDS combine over s;
// lanes 0..31 compute loss and wave-reduce -> one atomic per block.
__global__ __launch_bounds__(256) void loss_reduce_kernel(
    const float* __restrict__ part, const float* __restrict__ d12,
    float* __restrict__ out, int N)
{
    __shared__ float lr1[8][32];
    __shared__ float lr2[8][32];
    const int j = threadIdx.x & 31;
    const int s = threadIdx.x >> 5;
    const int i = blockIdx.x * 32 + j;

    float r1 = 0.f, r2 = 0.f;
    for (int sl = s; sl < NSLOT; sl += 8) {
        r1 += part[(size_t)sl * (2 * N) + i];
        r2 += part[(size_t)sl * (2 * N) + N + i];
    }
    lr1[s][j] = r1;
    lr2[s][j] = r2;
    __syncthreads();

    if (threadIdx.x < 32) {
        float a1 = 0.f, a2 = 0.f;
#pragma unroll
        for (int ss = 0; ss < 8; ++ss) { a1 += lr1[ss][j]; a2 += lr2[ss][j]; }
        float loss = 0.5f * (logf(a1 - E5) + logf(a2 - E5)) - d12[i];
#pragma unroll
        for (int off = 1; off < 32; off <<= 1)
            loss += __shfl_xor(loss, off, 64);
        if (j == 0) atomicAdd(out, loss / (float)N);
    }
}

extern "C" void kernel_launch(void* const* d_in, const int* in_sizes, int n_in,
                              void* d_out, int out_size, void* d_ws, size_t ws_size,
                              hipStream_t stream) {
    const float* h1 = (const float*)d_in[0];
    const float* h2 = (const float*)d_in[1];
    const int N = in_sizes[0] / D;   // 8192

    unsigned char* P = (unsigned char*)d_ws;                // 2N x 128 fp8, operand-major
    float* part = (float*)(P + (size_t)2 * N * D);          // 145 x 2N partials
    float* d12  = part + (size_t)NSLOT * 2 * N;             // N
    float* out  = (float*)d_out;

    normalize_kernel<<<N / 32, 256, 0, stream>>>(
        (const float4*)h1, (const float4*)h2, P, d12, out, N);

    dim3 grid(128, 17, 2);
    gram_mfma_kernel<<<grid, 256, 0, stream>>>(P, part, N);

    loss_reduce_kernel<<<N / 32, 256, 0, stream>>>(part, d12, out, N);
}